// Round 10
// baseline (377.041 us; speedup 1.0000x reference)
//
#include <hip/hip_runtime.h>
#include <hip/hip_bf16.h>
#include <stdint.h>

#define NEG_INF -100000000.0f

typedef __attribute__((ext_vector_type(8))) short bf16x8;
typedef __attribute__((ext_vector_type(4))) float f32x4;
typedef __attribute__((ext_vector_type(4))) int i32x4;
typedef __attribute__((ext_vector_type(2))) int i32x2;

// lgkm-only barrier: does NOT drain in-flight global (NT) stores.
#define LGKM_BAR()                                                \
    do {                                                          \
        asm volatile("s_waitcnt lgkmcnt(0)" ::: "memory");        \
        __builtin_amdgcn_s_barrier();                             \
        __builtin_amdgcn_sched_barrier(0);                        \
    } while (0)

static __device__ __forceinline__ short f2bf(float x) {
    unsigned u = __float_as_uint(x);
    u = u + 0x7FFFu + ((u >> 16) & 1u);
    return (short)(u >> 16);
}
static __device__ __forceinline__ float bf2f(short s) {
    return __uint_as_float(((unsigned)(unsigned short)s) << 16);
}

// ---------------- kernel 1: transpose + bf16-convert weights ----------------
__global__ void wtrans_kernel(const float* __restrict__ wq, const float* __restrict__ wk,
                              short* __restrict__ wtq, short* __restrict__ wtk) {
    __shared__ float tile[32][33];
    const float* w = blockIdx.z ? wk : wq;
    short* wt = blockIdx.z ? wtk : wtq;
    float scale = blockIdx.z ? 1.0f : 0.0625f;   // 1/sqrt(256) folded into wq
    int tx = threadIdx.x, ty = threadIdx.y;
    int c0 = blockIdx.x * 32;
    int k0 = blockIdx.y * 32;
#pragma unroll
    for (int i = 0; i < 4; i++)
        tile[ty + i * 8][tx] = w[(k0 + ty + i * 8) * 256 + c0 + tx];
    __syncthreads();
#pragma unroll
    for (int i = 0; i < 4; i++)
        wt[(c0 + ty + i * 8) * 256 + k0 + tx] = f2bf(tile[tx][ty + i * 8] * scale);
}

// ---------------- kernel 2: projection GEMM + (y==2) mask bit-pack ----------------
// y=0: Q, y=1: K -> fragment layout [b][dc 8][row 1024][ks 32] bf16
// y=2: pack mask plain row-major: word (row, j) bit c = mask[row][j*32+c]
__global__ __launch_bounds__(512, 4)
void proj_kernel(const float* __restrict__ qin, const float* __restrict__ kin,
                 const short* __restrict__ wtq, const short* __restrict__ wtk,
                 short* __restrict__ Qb, short* __restrict__ Kb,
                 const int* __restrict__ mask, unsigned* __restrict__ pmask) {
    if (blockIdx.y == 2) {
        int t = threadIdx.x;
        size_t row = (size_t)blockIdx.x * 64 + (t >> 3);
        int seg8 = t & 7;
        const int* mrow = mask + row * 1024;
#pragma unroll
        for (int jj = 0; jj < 4; jj++) {
            int j = seg8 + jj * 8;
            unsigned v = 0;
#pragma unroll
            for (int i = 0; i < 8; i++) {
                i32x4 x = __builtin_nontemporal_load(
                    reinterpret_cast<const i32x4*>(mrow + j * 32 + i * 4));
                v |= ((unsigned)x.x << (i * 4)) | ((unsigned)x.y << (i * 4 + 1)) |
                     ((unsigned)x.z << (i * 4 + 2)) | ((unsigned)x.w << (i * 4 + 3));
            }
            pmask[row * 32 + j] = v;
        }
        return;
    }

    const float* x  = blockIdx.y ? kin : qin;
    const short* wt = blockIdx.y ? wtk : wtq;
    short* outp     = blockIdx.y ? Kb  : Qb;

    __shared__ __align__(16) short sbuf[64 * 296];
    short* xlds = sbuf;                // [64 row][32 k]
    short* wlds = sbuf + 2048;         // [256 c][32 k]

    int t = threadIdx.x;
    int lane = t & 63, w = t >> 6;
    int l15 = lane & 15, g = lane >> 4;
    int rowbase = blockIdx.x * 64;

    f32x4 zero = {0.f, 0.f, 0.f, 0.f};
    f32x4 acc[4][2];
#pragma unroll
    for (int m = 0; m < 4; m++)
#pragma unroll
        for (int n = 0; n < 2; n++) acc[m][n] = zero;

    for (int dc = 0; dc < 8; dc++) {
        __syncthreads();
        {
            int row = t >> 3, seg = t & 7;
            f32x4 v = __builtin_nontemporal_load(
                reinterpret_cast<const f32x4*>(x + (size_t)(rowbase + row) * 256 + dc * 32 + seg * 4));
            short4 bb;
            bb.x = f2bf(v.x); bb.y = f2bf(v.y); bb.z = f2bf(v.z); bb.w = f2bf(v.w);
            *reinterpret_cast<short4*>(&xlds[row * 32 + seg * 4]) = bb;
        }
#pragma unroll
        for (int i = 0; i < 2; i++) {
            int idx = i * 512 + t;
            int c = idx >> 2, seg = idx & 3;
            int4 v = *reinterpret_cast<const int4*>(wt + c * 256 + dc * 32 + seg * 8);
            *reinterpret_cast<int4*>(&wlds[idx * 8]) = v;
        }
        __syncthreads();

        bf16x8 a[4], bfr[2];
#pragma unroll
        for (int m = 0; m < 4; m++)
            a[m] = *reinterpret_cast<const bf16x8*>(&xlds[(m * 16 + l15) * 32 + g * 8]);
#pragma unroll
        for (int n = 0; n < 2; n++) {
            int c = w * 32 + n * 16 + l15;
            bfr[n] = *reinterpret_cast<const bf16x8*>(&wlds[c * 32 + g * 8]);
        }
#pragma unroll
        for (int m = 0; m < 4; m++)
#pragma unroll
            for (int n = 0; n < 2; n++)
                acc[m][n] = __builtin_amdgcn_mfma_f32_16x16x32_bf16(a[m], bfr[n], acc[m][n], 0, 0, 0);
    }

    __syncthreads();
#pragma unroll
    for (int m = 0; m < 4; m++)
#pragma unroll
        for (int n = 0; n < 2; n++) {
            int col = w * 32 + n * 16 + l15;
#pragma unroll
            for (int r = 0; r < 4; r++)
                sbuf[(m * 16 + g * 4 + r) * 296 + col] = f2bf(acc[m][n][r]);
        }
    __syncthreads();

    int b8 = rowbase >> 10;
    int rloc = rowbase & 1023;
#pragma unroll
    for (int o = 0; o < 4; o++) {
        int gu = o * 512 + t;
        int dc = gu >> 8;
        int rem = gu & 255;
        int row = rem >> 2, kseg = rem & 3;
        int4 v = *reinterpret_cast<const int4*>(&sbuf[row * 296 + dc * 32 + kseg * 8]);
        size_t idx = (((size_t)b8 * 8 + dc) * 1024 + rloc + row) * 32 + kseg * 8;
        *reinterpret_cast<int4*>(outp + idx) = v;
    }
}

// ---------------- kernel 3a: QK^T -> U (bf16, row-major) ----------------
// Pure GEMM: frag-direct Q/K loads from L2, bf16 park in LDS, row-contiguous
// NT dwordx4 stores. No softmax state -> low VGPR, simple chain.
__global__ __launch_bounds__(512, 4)
void qkt_kernel(const short* __restrict__ Qs, const short* __restrict__ Ks,
                short* __restrict__ U) {
    const int RS = 1042;                                // padded (521 words: 2-way max on dump)
    __shared__ __align__(16) short ulds[16 * RS];       // 33344 B

    int t = threadIdx.x;
    int lane = t & 63, w = t >> 6;
    int l15 = lane & 15, g = lane >> 4;

    int bid = blockIdx.x;
    int wg = (bid & 7) * 256 + (bid >> 3);   // XCD swizzle: 8 batches per XCD
    int b = wg >> 5;
    int brow = (wg & 31) * 32;

    const short* qb = Qs + (size_t)b * 8 * 32768;
    const short* kb = Ks + (size_t)b * 8 * 32768;

    f32x4 zero = {0.f, 0.f, 0.f, 0.f};
    f32x4 acc[2][8];
#pragma unroll
    for (int m = 0; m < 2; m++)
#pragma unroll
        for (int n = 0; n < 8; n++) acc[m][n] = zero;

    for (int dc = 0; dc < 8; dc++) {
        const short* qc = qb + dc * 32768;
        const short* kc = kb + dc * 32768;
        bf16x8 a0 = *reinterpret_cast<const bf16x8*>(qc + (brow + l15) * 32 + g * 8);
        bf16x8 a1 = *reinterpret_cast<const bf16x8*>(qc + (brow + 16 + l15) * 32 + g * 8);
#pragma unroll
        for (int n = 0; n < 8; n++) {
            bf16x8 bf = *reinterpret_cast<const bf16x8*>(kc + (w * 128 + n * 16 + l15) * 32 + g * 8);
            acc[0][n] = __builtin_amdgcn_mfma_f32_16x16x32_bf16(a0, bf, acc[0][n], 0, 0, 0);
            acc[1][n] = __builtin_amdgcn_mfma_f32_16x16x32_bf16(a1, bf, acc[1][n], 0, 0, 0);
        }
    }

#pragma unroll
    for (int m = 0; m < 2; m++) {
        LGKM_BAR();    // prior park's reads done; NT stores stay in flight
#pragma unroll
        for (int n = 0; n < 8; n++)
#pragma unroll
            for (int r = 0; r < 4; r++)
                ulds[(g * 4 + r) * RS + w * 128 + n * 16 + l15] = f2bf(acc[m][n][r]);
        LGKM_BAR();

        // wave w stores park rows 2w, 2w+1 as contiguous 1KB wave-instructions
        short* ubase = U + ((size_t)b * 1024 + brow + m * 16) * 1024;
#pragma unroll
        for (int rr = 0; rr < 2; rr++) {
            int r2 = w * 2 + rr;
            short* urow = ubase + (size_t)r2 * 1024;
#pragma unroll
            for (int it = 0; it < 2; it++) {
                int col = lane * 8 + it * 512;
                i32x4 v = *reinterpret_cast<const i32x4*>(&ulds[r2 * RS + col]);
                __builtin_nontemporal_store(v, reinterpret_cast<i32x4*>(urow + col));
            }
        }
    }
}

// ---------------- kernel 3b: epilogue: tanh-clip + mask + log_softmax ----------------
// Pure streaming, ~40 VGPR -> high occupancy. One wave per row.
__global__ __launch_bounds__(256)
void epi_kernel(const short* __restrict__ U, const unsigned* __restrict__ pmask,
                float* __restrict__ out) {
    int t = threadIdx.x;
    int lane = t & 63, wv = t >> 6;
    size_t row = (size_t)blockIdx.x * 4 + wv;

    const short* urow = U + row * 1024;
    const unsigned* pmrow = pmask + row * 32;

    float uc[4][4];
    float psum = 0.f;
#pragma unroll
    for (int it = 0; it < 4; it++) {
        int c0 = lane * 4 + it * 256;
        i32x2 raw = __builtin_nontemporal_load(reinterpret_cast<const i32x2*>(urow + c0));
        unsigned bits = (pmrow[c0 >> 5] >> (c0 & 31)) & 0xF;
        short s4[4] = {(short)(raw.x & 0xFFFF), (short)(raw.x >> 16),
                       (short)(raw.y & 0xFFFF), (short)(raw.y >> 16)};
#pragma unroll
        for (int c = 0; c < 4; c++) {
            float u = bf2f(s4[c]);
            float e2 = __expf(2.0f * u);
            float tc = 10.0f - 20.0f / (e2 + 1.0f);   // 10*tanh(u)
            bool msk = (bits >> c) & 1;
            uc[it][c] = msk ? NEG_INF : tc;
            psum += msk ? 0.0f : __expf(tc);
        }
    }
    psum += __shfl_xor(psum, 1);
    psum += __shfl_xor(psum, 2);
    psum += __shfl_xor(psum, 4);
    psum += __shfl_xor(psum, 8);
    psum += __shfl_xor(psum, 16);
    psum += __shfl_xor(psum, 32);
    float lse = __logf(fmaxf(psum, 1e-30f));

    float* orow = out + row * 1024;
#pragma unroll
    for (int it = 0; it < 4; it++) {
        int c0 = lane * 4 + it * 256;
        f32x4 o = {uc[it][0] - lse, uc[it][1] - lse, uc[it][2] - lse, uc[it][3] - lse};
        __builtin_nontemporal_store(o, reinterpret_cast<f32x4*>(orow + c0));
    }
}

extern "C" void kernel_launch(void* const* d_in, const int* in_sizes, int n_in,
                              void* d_out, int out_size, void* d_ws, size_t ws_size,
                              hipStream_t stream) {
    const float* q  = (const float*)d_in[0];
    const float* k  = (const float*)d_in[1];
    const float* wq = (const float*)d_in[2];
    const float* wk = (const float*)d_in[3];
    const int* mask = (const int*)d_in[4];
    float* out = (float*)d_out;

    char* ws = (char*)d_ws;
    short* wtq = (short*)ws;                                   // 128KB
    short* wtk = (short*)(ws + 131072);                        // 128KB
    short* Qb  = (short*)(ws + 262144);                        // 32MB
    short* Kb  = (short*)(ws + 262144 + 33554432);             // 32MB
    unsigned* pmask = (unsigned*)(ws + 262144 + 2 * 33554432); // 8.4MB
    short* U = (short*)(ws + 262144 + 2 * 33554432 + 8388608); // 128MB

    wtrans_kernel<<<dim3(8, 8, 2), dim3(32, 8), 0, stream>>>(wq, wk, wtq, wtk);
    proj_kernel<<<dim3(1024, 3), 512, 0, stream>>>(q, k, wtq, wtk, Qb, Kb, mask, pmask);
    qkt_kernel<<<dim3(2048), 512, 0, stream>>>(Qb, Kb, U);
    epi_kernel<<<dim3(16384), 256, 0, stream>>>(U, pmask, out);
}

// Round 11
// 215.476 us; speedup vs baseline: 1.7498x; 1.7498x over previous
//
#include <hip/hip_runtime.h>
#include <hip/hip_bf16.h>
#include <stdint.h>

#define NEG_INF -100000000.0f

typedef __attribute__((ext_vector_type(8))) short bf16x8;
typedef __attribute__((ext_vector_type(4))) float f32x4;
typedef __attribute__((ext_vector_type(4))) int i32x4;

// lgkm-only barrier: does NOT drain in-flight global (NT) stores/loads.
#define LGKM_BAR()                                                \
    do {                                                          \
        asm volatile("s_waitcnt lgkmcnt(0)" ::: "memory");        \
        __builtin_amdgcn_s_barrier();                             \
        __builtin_amdgcn_sched_barrier(0);                        \
    } while (0)

static __device__ __forceinline__ short f2bf(float x) {
    unsigned u = __float_as_uint(x);
    u = u + 0x7FFFu + ((u >> 16) & 1u);
    return (short)(u >> 16);
}

// ---------------- kernel 1: transpose + bf16-convert weights ----------------
__global__ void wtrans_kernel(const float* __restrict__ wq, const float* __restrict__ wk,
                              short* __restrict__ wtq, short* __restrict__ wtk) {
    __shared__ float tile[32][33];
    const float* w = blockIdx.z ? wk : wq;
    short* wt = blockIdx.z ? wtk : wtq;
    float scale = blockIdx.z ? 1.0f : 0.0625f;   // 1/sqrt(256) folded into wq
    int tx = threadIdx.x, ty = threadIdx.y;
    int c0 = blockIdx.x * 32;
    int k0 = blockIdx.y * 32;
#pragma unroll
    for (int i = 0; i < 4; i++)
        tile[ty + i * 8][tx] = w[(k0 + ty + i * 8) * 256 + c0 + tx];
    __syncthreads();
#pragma unroll
    for (int i = 0; i < 4; i++)
        wt[(c0 + ty + i * 8) * 256 + k0 + tx] = f2bf(tile[tx][ty + i * 8] * scale);
}

// ---------------- kernel 2: projection GEMM (pipelined) + (y==2) mask pack ----------------
// y=0: Q, y=1: K -> fragment layout [b][dc 8][row 1024][ks 32] bf16
// y=2: pack mask; word (row,j) bit (i*4+c) = mask[row][j*4+i*128+c]
__global__ __launch_bounds__(512, 4)
void proj_kernel(const float* __restrict__ qin, const float* __restrict__ kin,
                 const short* __restrict__ wtq, const short* __restrict__ wtk,
                 short* __restrict__ Qb, short* __restrict__ Kb,
                 const int* __restrict__ mask, unsigned* __restrict__ pmask) {
    if (blockIdx.y == 2) {
        int t = threadIdx.x;
        size_t row = (size_t)blockIdx.x * 64 + (t >> 3);
        int seg8 = t & 7;
        const int* mrow = mask + row * 1024;
#pragma unroll
        for (int jj = 0; jj < 4; jj++) {
            int j = seg8 + jj * 8;
            unsigned v = 0;
#pragma unroll
            for (int i = 0; i < 8; i++) {
                i32x4 x = __builtin_nontemporal_load(
                    reinterpret_cast<const i32x4*>(mrow + j * 4 + i * 128));
                unsigned nib = (unsigned)(x.x | (x.y << 1) | (x.z << 2) | (x.w << 3));
                v |= nib << (i * 4);
            }
            pmask[row * 32 + j] = v;
        }
        return;
    }

    const float* x  = blockIdx.y ? kin : qin;
    const short* wt = blockIdx.y ? wtk : wtq;
    short* outp     = blockIdx.y ? Kb  : Qb;

    __shared__ __align__(16) char slds[40960];     // 2 staging bufs / C-dump overlay
    short* xl0 = (short*)slds;          // [64 row][32 k]
    short* wl0 = xl0 + 2048;            // [256 c][32 k]
    short* xl1 = (short*)(slds + 20480);
    short* wl1 = xl1 + 2048;

    int t = threadIdx.x;
    int lane = t & 63, w = t >> 6;
    int l15 = lane & 15, g = lane >> 4;
    int rowbase = blockIdx.x * 64;

    int srow = t >> 3, sseg = t & 7;
    const float* xrow = x + (size_t)(rowbase + srow) * 256 + sseg * 4;
    int wc0 = t >> 2, wseg0 = t & 3;                // staging unit i=0
    int wc1 = (512 + t) >> 2, wseg1 = t & 3;        // staging unit i=1

    f32x4 zero = {0.f, 0.f, 0.f, 0.f};
    f32x4 acc[4][2];
#pragma unroll
    for (int m = 0; m < 4; m++)
#pragma unroll
        for (int n = 0; n < 2; n++) acc[m][n] = zero;

    // prologue: stage dc=0 into buf0
    {
        f32x4 xv = __builtin_nontemporal_load(reinterpret_cast<const f32x4*>(xrow));
        int4 wv0 = *reinterpret_cast<const int4*>(wt + wc0 * 256 + wseg0 * 8);
        int4 wv1 = *reinterpret_cast<const int4*>(wt + wc1 * 256 + wseg1 * 8);
        short4 bb; bb.x = f2bf(xv.x); bb.y = f2bf(xv.y); bb.z = f2bf(xv.z); bb.w = f2bf(xv.w);
        *reinterpret_cast<short4*>(&xl0[srow * 32 + sseg * 4]) = bb;
        *reinterpret_cast<int4*>(&wl0[(size_t)t * 8]) = wv0;
        *reinterpret_cast<int4*>(&wl0[((size_t)512 + t) * 8]) = wv1;
    }
    LGKM_BAR();

#pragma unroll
    for (int dc = 0; dc < 8; dc++) {
        short* xc   = (dc & 1) ? xl1 : xl0;
        short* wcur = (dc & 1) ? wl1 : wl0;
        short* xn   = (dc & 1) ? xl0 : xl1;
        short* wn   = (dc & 1) ? wl0 : wl1;

        f32x4 xv; int4 wv0, wv1;
        if (dc < 7) {   // issue next-chunk loads early (cover under MFMA)
            xv  = __builtin_nontemporal_load(reinterpret_cast<const f32x4*>(xrow + (dc + 1) * 32));
            wv0 = *reinterpret_cast<const int4*>(wt + wc0 * 256 + (dc + 1) * 32 + wseg0 * 8);
            wv1 = *reinterpret_cast<const int4*>(wt + wc1 * 256 + (dc + 1) * 32 + wseg1 * 8);
        }

        bf16x8 a[4], bfr[2];
#pragma unroll
        for (int m = 0; m < 4; m++)
            a[m] = *reinterpret_cast<const bf16x8*>(&xc[(m * 16 + l15) * 32 + g * 8]);
#pragma unroll
        for (int n = 0; n < 2; n++) {
            int c = w * 32 + n * 16 + l15;
            bfr[n] = *reinterpret_cast<const bf16x8*>(&wcur[c * 32 + g * 8]);
        }
#pragma unroll
        for (int m = 0; m < 4; m++)
#pragma unroll
            for (int n = 0; n < 2; n++)
                acc[m][n] = __builtin_amdgcn_mfma_f32_16x16x32_bf16(a[m], bfr[n], acc[m][n], 0, 0, 0);

        if (dc < 7) {
            short4 bb; bb.x = f2bf(xv.x); bb.y = f2bf(xv.y); bb.z = f2bf(xv.z); bb.w = f2bf(xv.w);
            *reinterpret_cast<short4*>(&xn[srow * 32 + sseg * 4]) = bb;
            *reinterpret_cast<int4*>(&wn[(size_t)t * 8]) = wv0;
            *reinterpret_cast<int4*>(&wn[((size_t)512 + t) * 8]) = wv1;
            LGKM_BAR();   // writes visible; all waves' reads of buf[cur] done
        }
    }

    LGKM_BAR();   // frag reads done before dump overlay
    short* sdump = (short*)slds;    // [64 row][296]
#pragma unroll
    for (int m = 0; m < 4; m++)
#pragma unroll
        for (int n = 0; n < 2; n++) {
            int col = w * 32 + n * 16 + l15;
#pragma unroll
            for (int r = 0; r < 4; r++)
                sdump[(m * 16 + g * 4 + r) * 296 + col] = f2bf(acc[m][n][r]);
        }
    LGKM_BAR();

    int b8 = rowbase >> 10;
    int rloc = rowbase & 1023;
#pragma unroll
    for (int o = 0; o < 4; o++) {
        int gu = o * 512 + t;
        int dc = gu >> 8;
        int rem = gu & 255;
        int row = rem >> 2, kseg = rem & 3;
        int4 v = *reinterpret_cast<const int4*>(&sdump[row * 296 + dc * 32 + kseg * 8]);
        size_t idx = (((size_t)b8 * 8 + dc) * 1024 + rloc + row) * 32 + kseg * 8;
        *reinterpret_cast<int4*>(outp + idx) = v;
    }
}

// ---------------- kernel 3: fused QK^T + tanh-clip + mask + log_softmax ----------------
// bf16 double-buffered park: 2 barriers total; m=1 dump overlaps m=0 finish.
__global__ __launch_bounds__(512, 4)
void attn_kernel(const short* __restrict__ Qs, const short* __restrict__ Ks,
                 const unsigned* __restrict__ pmask, float* __restrict__ out) {
    const int RSB = 1034;                              // shorts/row: <=2-way banks everywhere
    __shared__ __align__(16) short ulds0[16 * RSB];    // 33,088 B
    __shared__ __align__(16) short ulds1[16 * RSB];    // total 66,176 B -> 2 blocks/CU

    int t = threadIdx.x;
    int lane = t & 63, w = t >> 6;
    int l15 = lane & 15, g = lane >> 4;

    int bid = blockIdx.x;
    int wg = (bid & 7) * 256 + (bid >> 3);   // XCD swizzle
    int b = wg >> 5;
    int brow = (wg & 31) * 32;

    const unsigned* pm = pmask + ((size_t)b * 1024 + brow) * 32;
    unsigned mw0 = pm[t];
    unsigned mw1 = pm[512 + t];

    const short* qb = Qs + (size_t)b * 8 * 32768;
    const short* kb = Ks + (size_t)b * 8 * 32768;

    f32x4 zero = {0.f, 0.f, 0.f, 0.f};
    f32x4 acc[2][8];
#pragma unroll
    for (int m = 0; m < 2; m++)
#pragma unroll
        for (int n = 0; n < 8; n++) acc[m][n] = zero;

    for (int dc = 0; dc < 8; dc++) {
        const short* qc = qb + dc * 32768;
        const short* kc = kb + dc * 32768;
        bf16x8 a0 = *reinterpret_cast<const bf16x8*>(qc + (brow + l15) * 32 + g * 8);
        bf16x8 a1 = *reinterpret_cast<const bf16x8*>(qc + (brow + 16 + l15) * 32 + g * 8);
#pragma unroll
        for (int n = 0; n < 8; n++) {
            bf16x8 bf = *reinterpret_cast<const bf16x8*>(kc + (w * 128 + n * 16 + l15) * 32 + g * 8);
            acc[0][n] = __builtin_amdgcn_mfma_f32_16x16x32_bf16(a0, bf, acc[0][n], 0, 0, 0);
            acc[1][n] = __builtin_amdgcn_mfma_f32_16x16x32_bf16(a1, bf, acc[1][n], 0, 0, 0);
        }
    }

    int prow = t >> 5;         // 0..15
    int j = t & 31;

    // dump m=0 -> buf0
#pragma unroll
    for (int n = 0; n < 8; n++)
#pragma unroll
        for (int r = 0; r < 4; r++)
            ulds0[(g * 4 + r) * RSB + w * 128 + n * 16 + l15] = f2bf(acc[0][n][r]);
    LGKM_BAR();

    // dump m=1 -> buf1 (overlaps m=0 finish; disjoint buffers)
#pragma unroll
    for (int n = 0; n < 8; n++)
#pragma unroll
        for (int r = 0; r < 4; r++)
            ulds1[(g * 4 + r) * RSB + w * 128 + n * 16 + l15] = f2bf(acc[1][n][r]);

#pragma unroll
    for (int m = 0; m < 2; m++) {
        short* buf = m ? ulds1 : ulds0;
        unsigned bits = m ? mw1 : mw0;
        short* urow = buf + prow * RSB;

        // pass 1: tanh-clip + mask + exp-sum; park uc (bf16) in place
        float psum = 0.f;
#pragma unroll
        for (int i = 0; i < 8; i++) {
            int col = j * 4 + i * 128;
            unsigned lo = *reinterpret_cast<const unsigned*>(&urow[col]);
            unsigned hi = *reinterpret_cast<const unsigned*>(&urow[col + 2]);
            float uv[4] = {__uint_as_float(lo << 16), __uint_as_float(lo & 0xffff0000u),
                           __uint_as_float(hi << 16), __uint_as_float(hi & 0xffff0000u)};
            unsigned short ucb[4];
#pragma unroll
            for (int c = 0; c < 4; c++) {
                float e2 = __expf(2.0f * uv[c]);
                float tc = 10.0f - 20.0f / (e2 + 1.0f);   // 10*tanh(u)
                bool msk = (bits >> (i * 4 + c)) & 1;
                float uc = msk ? NEG_INF : tc;
                ucb[c] = (unsigned short)f2bf(uc);
                psum += msk ? 0.0f : __expf(tc);
            }
            *reinterpret_cast<unsigned*>(&urow[col]) = (unsigned)ucb[0] | ((unsigned)ucb[1] << 16);
            *reinterpret_cast<unsigned*>(&urow[col + 2]) = (unsigned)ucb[2] | ((unsigned)ucb[3] << 16);
        }
        psum += __shfl_xor(psum, 1);
        psum += __shfl_xor(psum, 2);
        psum += __shfl_xor(psum, 4);
        psum += __shfl_xor(psum, 8);
        psum += __shfl_xor(psum, 16);
        float lse = __logf(fmaxf(psum, 1e-30f));
        float lse0 = __shfl(lse, 0);    // row 2w
        float lse1 = __shfl(lse, 32);   // row 2w+1

        // pass 2: wave w owns park rows 2w,2w+1 (wave-local); full-wave NT stores
        float* obase = out + ((size_t)b * 1024 + brow + m * 16) * 1024;
#pragma unroll
        for (int rr = 0; rr < 2; rr++) {
            int r2 = w * 2 + rr;
            float lser = rr ? lse1 : lse0;
            const short* ur2 = buf + r2 * RSB;
            float* orow = obase + (size_t)r2 * 1024;
#pragma unroll
            for (int i2 = 0; i2 < 4; i2++) {
                int col = lane * 4 + i2 * 256;
                unsigned lo = *reinterpret_cast<const unsigned*>(&ur2[col]);
                unsigned hi = *reinterpret_cast<const unsigned*>(&ur2[col + 2]);
                f32x4 o = {__uint_as_float(lo << 16) - lser,
                           __uint_as_float(lo & 0xffff0000u) - lser,
                           __uint_as_float(hi << 16) - lser,
                           __uint_as_float(hi & 0xffff0000u) - lser};
                __builtin_nontemporal_store(o, reinterpret_cast<f32x4*>(orow + col));
            }
        }
        if (m == 0) LGKM_BAR();   // buf1 dumps (all waves) visible before pass 1 on buf1
    }
}

extern "C" void kernel_launch(void* const* d_in, const int* in_sizes, int n_in,
                              void* d_out, int out_size, void* d_ws, size_t ws_size,
                              hipStream_t stream) {
    const float* q  = (const float*)d_in[0];
    const float* k  = (const float*)d_in[1];
    const float* wq = (const float*)d_in[2];
    const float* wk = (const float*)d_in[3];
    const int* mask = (const int*)d_in[4];
    float* out = (float*)d_out;

    char* ws = (char*)d_ws;
    short* wtq = (short*)ws;                                   // 128KB
    short* wtk = (short*)(ws + 131072);                        // 128KB
    short* Qb  = (short*)(ws + 262144);                        // 32MB
    short* Kb  = (short*)(ws + 262144 + 33554432);             // 32MB
    unsigned* pmask = (unsigned*)(ws + 262144 + 2 * 33554432); // 8.4MB

    wtrans_kernel<<<dim3(8, 8, 2), dim3(32, 8), 0, stream>>>(wq, wk, wtq, wtk);
    proj_kernel<<<dim3(1024, 3), 512, 0, stream>>>(q, k, wtq, wtk, Qb, Kb, mask, pmask);
    attn_kernel<<<dim3(2048), 512, 0, stream>>>(Qb, Kb, pmask, out);
}